// Round 10
// baseline (272.669 us; speedup 1.0000x reference)
//
#include <hip/hip_runtime.h>
#include <hip/hip_bf16.h>
#include <stdint.h>

#define S_LEN 2048
#define DH    64
#define NBH   64          // B*H = 4*16
#define QR    128         // q-rows per workgroup
#define KTI   64          // k-cols per tile
#define NT    (S_LEN / KTI)   // 32 tiles
#define NTHR  512
#define SCALE2 (0.125f * 1.44269504f)   // (1/sqrt(64)) * log2(e)
#define EXPB2  23.0f                    // fixed softmax bias (base-2)

// XOR swizzle within a [R][64]-short tile: spreads same-column reads across
// 8 distinct 16B slots (T2). Pure function of (row,col); 16B-chunk bijective.
#define SWZ(row, col) ((col) ^ (((row) & 7) << 3))

using f32x4   = __attribute__((ext_vector_type(4))) float;
using short8v = __attribute__((ext_vector_type(8))) short;
using short4v = __attribute__((ext_vector_type(4))) short;

__device__ __forceinline__ short f2bf(float f) {
    union { float f; uint32_t u; } v; v.f = f;
    uint32_t u = v.u;
    return (short)((u + 0x7FFFu + ((u >> 16) & 1u)) >> 16);  // RNE
}

// ---------- merged prep kernel ----------
// blocks [0,4096): K fp32 -> bf16         (reads 33.5MB, writes 16.7MB)
// blocks [4096,6144): V fp32 -> bf16 V^T  (reads 33.5MB, writes 16.7MB)
// blocks [6144,7168): mask -> packed bits (reads 16MB,   writes 1MB)
#define PREP_CONV_BLOCKS  4096
#define PREP_TRANS_BLOCKS 2048
#define PREP_MASK_BLOCKS  1024

__global__ __launch_bounds__(256)
void prep_kernel(const float* __restrict__ K, const float* __restrict__ V,
                 const int* __restrict__ mask,
                 uint16_t* __restrict__ Kb, uint16_t* __restrict__ Vt,
                 uint32_t* __restrict__ pmL)
{
    const int b = blockIdx.x;
    if (b < PREP_CONV_BLOCKS) {
        size_t i = ((size_t)b * 256 + threadIdx.x) * 8;
        float4 a = *reinterpret_cast<const float4*>(K + i);
        float4 c = *reinterpret_cast<const float4*>(K + i + 4);
        short8v o;
        o[0] = f2bf(a.x); o[1] = f2bf(a.y); o[2] = f2bf(a.z); o[3] = f2bf(a.w);
        o[4] = f2bf(c.x); o[5] = f2bf(c.y); o[6] = f2bf(c.z); o[7] = f2bf(c.w);
        *reinterpret_cast<short8v*>(Kb + i) = o;
    } else if (b < PREP_CONV_BLOCKS + PREP_TRANS_BLOCKS) {
        __shared__ short Ts[DH][72];
        int b2 = b - PREP_CONV_BLOCKS;
        int bh = b2 >> 5;
        int t  = b2 & 31;
        const float* Vb = V + ((size_t)bh * S_LEN + t * KTI) * DH;
        int tid = threadIdx.x;
        #pragma unroll
        for (int i = 0; i < 4; ++i) {
            int lin = tid + i * 256;          // 0..1023 (float4 index)
            int row = lin >> 4;
            int c4  = (lin & 15) << 2;
            float4 v4 = *reinterpret_cast<const float4*>(Vb + row * DH + c4);
            Ts[c4 + 0][row] = f2bf(v4.x);
            Ts[c4 + 1][row] = f2bf(v4.y);
            Ts[c4 + 2][row] = f2bf(v4.z);
            Ts[c4 + 3][row] = f2bf(v4.w);
        }
        __syncthreads();
        #pragma unroll
        for (int i = 0; i < 2; ++i) {
            int lin = tid + i * 256;          // 0..511 (short8 index)
            int d   = lin >> 3;
            int k8  = (lin & 7) << 3;
            short8v o = *reinterpret_cast<const short8v*>(&Ts[d][k8]);
            *reinterpret_cast<short8v*>(Vt + ((size_t)bh * DH + d) * S_LEN + t * KTI + k8) = o;
        }
    } else {
        int tid = (b - PREP_CONV_BLOCKS - PREP_TRANS_BLOCKS) * 256 + threadIdx.x;
        int c  = tid & 15;
        int t  = (tid >> 4) & (NT - 1);
        int q4 = tid >> 9;
        uint32_t bits = 0;
        #pragma unroll
        for (int r = 0; r < 4; ++r)
            #pragma unroll
            for (int n = 0; n < 4; ++n) {
                int q = q4 * 4 + r;
                int k = t * KTI + n * 16 + c;
                if (mask[q * S_LEN + k]) bits |= 1u << (r * 4 + n);
            }
        pmL[tid] = bits;
    }
}

// ---------- main attention kernel (fused, 48KB LDS, 3 blocks/CU) ----------

__global__ __launch_bounds__(NTHR, 6)
void attn_kernel(const float* __restrict__ Q, const uint16_t* __restrict__ Kbf,
                 const uint16_t* __restrict__ VTb, const uint32_t* __restrict__ pmask,
                 float* __restrict__ outC, float* __restrict__ outA)
{
    __shared__ short Ks[2][KTI][64];     // dbuf K tile, XOR-swizzled   (16 KB)
    __shared__ short VT[2][DH][64];      // dbuf V^T tile, XOR-swizzled (16 KB)
    __shared__ short Ps[8][16][64];      // per-wave P tile, swizzled   (16 KB)

    // XCD-aware swizzle (T1): XCD c (= wg%8) serves bh in [8c, 8c+8); all 16
    // q-blocks of one bh consecutive -> per-XCD K/V working set ~512KB << 4MB L2.
    const int wg  = blockIdx.x;          // 0..1023
    const int k_  = wg >> 3;
    const int bh  = (wg & 7) * 8 + (k_ >> 4);
    const int q0  = (k_ & 15) * QR;

    const int tid = threadIdx.x;
    const int w   = tid >> 6;
    const int l   = tid & 63;
    const int l16 = l & 15;
    const int g   = l >> 4;
    const int srow = tid >> 3;           // staging row (0..63)
    const int scol = (tid & 7) << 3;     // staging col (0,8,...,56)
    const int sscol = SWZ(srow, scol);   // swizzled staging col

    const float*    Qb  = Q   + ((size_t)bh * S_LEN + q0) * DH;
    const uint16_t* Kbb = Kbf + (size_t)bh * S_LEN * DH;       // [s][d]
    const uint16_t* Vbb = VTb + (size_t)bh * DH * S_LEN;       // [d][s]
    float* Cb = outC + ((size_t)bh * S_LEN + q0) * DH;
    float* Ab = outA + (size_t)bh * S_LEN * S_LEN + (size_t)q0 * S_LEN;

    // ---- Q A-fragments loaded per-lane directly (no LDS; reused in both phases) ----
    short8v aq0, aq1;
    {
        const float* qp = Qb + (w * 16 + l16) * DH;
        float4 a0 = *reinterpret_cast<const float4*>(qp + g * 8);
        float4 a1 = *reinterpret_cast<const float4*>(qp + g * 8 + 4);
        float4 a2 = *reinterpret_cast<const float4*>(qp + 32 + g * 8);
        float4 a3 = *reinterpret_cast<const float4*>(qp + 32 + g * 8 + 4);
        aq0[0] = f2bf(a0.x); aq0[1] = f2bf(a0.y); aq0[2] = f2bf(a0.z); aq0[3] = f2bf(a0.w);
        aq0[4] = f2bf(a1.x); aq0[5] = f2bf(a1.y); aq0[6] = f2bf(a1.z); aq0[7] = f2bf(a1.w);
        aq1[0] = f2bf(a2.x); aq1[1] = f2bf(a2.y); aq1[2] = f2bf(a2.z); aq1[3] = f2bf(a2.w);
        aq1[4] = f2bf(a3.x); aq1[5] = f2bf(a3.y); aq1[6] = f2bf(a3.z); aq1[7] = f2bf(a3.w);
    }

    const uint32_t* pmb = pmask + (size_t)((q0 >> 2) + (w << 2) + g) * (NT * 16) + l16;

    // B-frag swizzled column offsets (row = n*16+l16 has same (row&7) = l16&7)
    const int bc0 = SWZ(l16, g * 8);
    const int bc1 = SWZ(l16, 32 + g * 8);

    // ================= phase 1: softmax denominators (fixed-bias, no max) =================
    float ls[4] = {0.f, 0.f, 0.f, 0.f};
    {
        short8v kk = *reinterpret_cast<const short8v*>(Kbb + (size_t)srow * DH + scol);
        *reinterpret_cast<short8v*>(&Ks[0][srow][sscol]) = kk;
    }
    __syncthreads();

    for (int t = 0; t < NT; ++t) {
        const int  cur  = t & 1;
        const bool more = (t + 1 < NT);
        short8v nk;
        if (more)
            nk = *reinterpret_cast<const short8v*>(Kbb + (size_t)((t + 1) * KTI + srow) * DH + scol);

        uint32_t mb = pmb[t << 4];

        f32x4 acc[4];
        #pragma unroll
        for (int n = 0; n < 4; ++n) {
            short8v b0 = *reinterpret_cast<const short8v*>(&Ks[cur][n * 16 + l16][bc0]);
            short8v b1 = *reinterpret_cast<const short8v*>(&Ks[cur][n * 16 + l16][bc1]);
            f32x4 a = {0.f, 0.f, 0.f, 0.f};
            a = __builtin_amdgcn_mfma_f32_16x16x32_bf16(aq0, b0, a, 0, 0, 0);
            a = __builtin_amdgcn_mfma_f32_16x16x32_bf16(aq1, b1, a, 0, 0, 0);
            acc[n] = a;
        }

        #pragma unroll
        for (int n = 0; n < 4; ++n)
            #pragma unroll
            for (int r = 0; r < 4; ++r) {
                float e = __builtin_amdgcn_exp2f(acc[n][r] * SCALE2 - EXPB2);
                ls[r] += ((mb >> (r * 4 + n)) & 1u) ? e : 0.f;
            }

        if (more)
            *reinterpret_cast<short8v*>(&Ks[cur ^ 1][srow][sscol]) = nk;
        __syncthreads();
    }

    // reduce row sums across the 16-lane group, once
    float li[4];
    #pragma unroll
    for (int r = 0; r < 4; ++r) {
        float v = ls[r];
        v += __shfl_xor(v, 1);
        v += __shfl_xor(v, 2);
        v += __shfl_xor(v, 4);
        v += __shfl_xor(v, 8);
        li[r] = 1.0f / v;
    }

    f32x4 acco[4];
    #pragma unroll
    for (int n = 0; n < 4; ++n) acco[n] = (f32x4){0.f, 0.f, 0.f, 0.f};

    // ================= phase 2: attn write + PV (one barrier per tile) =================
    {
        short8v kk = *reinterpret_cast<const short8v*>(Kbb + (size_t)srow * DH + scol);
        *reinterpret_cast<short8v*>(&Ks[0][srow][sscol]) = kk;
        short8v vv = *reinterpret_cast<const short8v*>(Vbb + (size_t)srow * S_LEN + scol);
        *reinterpret_cast<short8v*>(&VT[0][srow][sscol]) = vv;
    }
    __syncthreads();

    for (int t = 0; t < NT; ++t) {
        const int  cur  = t & 1;
        const bool more = (t + 1 < NT);
        short8v nk, nv;
        if (more) {
            nk = *reinterpret_cast<const short8v*>(Kbb + (size_t)((t + 1) * KTI + srow) * DH + scol);
            nv = *reinterpret_cast<const short8v*>(Vbb + (size_t)srow * S_LEN + (t + 1) * KTI + scol);
        }
        uint32_t mb = pmb[t << 4];

        f32x4 acc[4];
        #pragma unroll
        for (int n = 0; n < 4; ++n) {
            short8v b0 = *reinterpret_cast<const short8v*>(&Ks[cur][n * 16 + l16][bc0]);
            short8v b1 = *reinterpret_cast<const short8v*>(&Ks[cur][n * 16 + l16][bc1]);
            f32x4 a = {0.f, 0.f, 0.f, 0.f};
            a = __builtin_amdgcn_mfma_f32_16x16x32_bf16(aq0, b0, a, 0, 0, 0);
            a = __builtin_amdgcn_mfma_f32_16x16x32_bf16(aq1, b1, a, 0, 0, 0);
            acc[n] = a;
        }

        // normalized probabilities -> Ps (bf16, A-frag layout, swizzled)
        #pragma unroll
        for (int n = 0; n < 4; ++n)
            #pragma unroll
            for (int r = 0; r < 4; ++r) {
                float e = __builtin_amdgcn_exp2f(acc[n][r] * SCALE2 - EXPB2) * li[r];
                float p = ((mb >> (r * 4 + n)) & 1u) ? e : 0.0f;
                Ps[w][4 * g + r][SWZ(4 * g + r, n * 16 + l16)] = f2bf(p);
            }

        // order the Ps short-writes before the vector readback (TBAA-proof)
        asm volatile("" ::: "memory");

        // attn store: full 256B row-chunks as f32x4, nontemporal
        {
            float* Aw = Ab + (size_t)(w * 16) * S_LEN + t * KTI;
            #pragma unroll
            for (int j = 0; j < 4; ++j) {
                int r4 = 4 * j + (l >> 4);
                short4v pv4 = *reinterpret_cast<const short4v*>(
                    &Ps[w][r4][SWZ(r4, (l & 15) * 4)]);
                f32x4 o;
                o[0] = __builtin_bit_cast(float, ((uint32_t)(uint16_t)pv4[0]) << 16);
                o[1] = __builtin_bit_cast(float, ((uint32_t)(uint16_t)pv4[1]) << 16);
                o[2] = __builtin_bit_cast(float, ((uint32_t)(uint16_t)pv4[2]) << 16);
                o[3] = __builtin_bit_cast(float, ((uint32_t)(uint16_t)pv4[3]) << 16);
                __builtin_nontemporal_store(o,
                    reinterpret_cast<f32x4*>(Aw + (size_t)r4 * S_LEN + (l & 15) * 4));
            }
        }

        // PV: O += P(16xKTI) * V(KTIxDH)
        short8v ap0 = *reinterpret_cast<const short8v*>(&Ps[w][l16][bc0]);
        short8v ap1 = *reinterpret_cast<const short8v*>(&Ps[w][l16][bc1]);
        #pragma unroll
        for (int n = 0; n < 4; ++n) {
            short8v b0 = *reinterpret_cast<const short8v*>(&VT[cur][n * 16 + l16][bc0]);
            short8v b1 = *reinterpret_cast<const short8v*>(&VT[cur][n * 16 + l16][bc1]);
            acco[n] = __builtin_amdgcn_mfma_f32_16x16x32_bf16(ap0, b0, acco[n], 0, 0, 0);
            acco[n] = __builtin_amdgcn_mfma_f32_16x16x32_bf16(ap1, b1, acco[n], 0, 0, 0);
        }

        // both K and V double-buffered: write cur^1, single barrier
        if (more) {
            *reinterpret_cast<short8v*>(&Ks[cur ^ 1][srow][sscol]) = nk;
            *reinterpret_cast<short8v*>(&VT[cur ^ 1][srow][sscol]) = nv;
        }
        __syncthreads();
    }

    // ---- write context ----
    #pragma unroll
    for (int n = 0; n < 4; ++n)
        #pragma unroll
        for (int r = 0; r < 4; ++r)
            Cb[(w * 16 + 4 * g + r) * DH + n * 16 + l16] = acco[n][r];
}

extern "C" void kernel_launch(void* const* d_in, const int* in_sizes, int n_in,
                              void* d_out, int out_size, void* d_ws, size_t ws_size,
                              hipStream_t stream)
{
    const float* Q    = (const float*)d_in[0];
    const float* K    = (const float*)d_in[1];
    const float* V    = (const float*)d_in[2];
    const int*   mask = (const int*)d_in[3];

    float* outC = (float*)d_out;
    float* outA = (float*)d_out + (size_t)NBH * S_LEN * DH;   // context first, then attn

    char* ws = (char*)d_ws;
    uint32_t* pmL = (uint32_t*)ws;                             // 1 MB packed mask
    uint16_t* Kbf = (uint16_t*)(ws + (1 << 20));               // 16 MB bf16 K
    uint16_t* VTb = (uint16_t*)(ws + (17 << 20));              // 16 MB bf16 V^T

    prep_kernel<<<dim3(PREP_CONV_BLOCKS + PREP_TRANS_BLOCKS + PREP_MASK_BLOCKS),
                  256, 0, stream>>>(K, V, mask, Kbf, VTb, pmL);
    attn_kernel<<<dim3(NBH * (S_LEN / QR)), NTHR, 0, stream>>>(Q, Kbf, VTb, pmL, outC, outA);
}

// Round 11
// 257.811 us; speedup vs baseline: 1.0576x; 1.0576x over previous
//
#include <hip/hip_runtime.h>
#include <hip/hip_bf16.h>
#include <stdint.h>

#define S_LEN 2048
#define DH    64
#define NBH   64          // B*H = 4*16
#define QR    128         // q-rows per workgroup
#define KTI   64          // k-cols per tile
#define NT    (S_LEN / KTI)   // 32 tiles
#define NTHR  512
#define SCALE2 (0.125f * 1.44269504f)   // (1/sqrt(64)) * log2(e)
#define EXPB2  23.0f                    // fixed softmax bias (base-2)

using f32x4   = __attribute__((ext_vector_type(4))) float;
using short8v = __attribute__((ext_vector_type(8))) short;
using short4v = __attribute__((ext_vector_type(4))) short;

__device__ __forceinline__ short f2bf(float f) {
    union { float f; uint32_t u; } v; v.f = f;
    uint32_t u = v.u;
    return (short)((u + 0x7FFFu + ((u >> 16) & 1u)) >> 16);  // RNE
}

// ---------- merged prep kernel (one launch: K-conv | V-transpose | mask-pack) ----------
#define PREP_CONV_BLOCKS  4096
#define PREP_TRANS_BLOCKS 2048
#define PREP_MASK_BLOCKS  1024

__global__ __launch_bounds__(256)
void prep_kernel(const float* __restrict__ K, const float* __restrict__ V,
                 const int* __restrict__ mask,
                 uint16_t* __restrict__ Kb, uint16_t* __restrict__ Vt,
                 uint32_t* __restrict__ pmL)
{
    const int b = blockIdx.x;
    if (b < PREP_CONV_BLOCKS) {
        size_t i = ((size_t)b * 256 + threadIdx.x) * 8;
        float4 a = *reinterpret_cast<const float4*>(K + i);
        float4 c = *reinterpret_cast<const float4*>(K + i + 4);
        short8v o;
        o[0] = f2bf(a.x); o[1] = f2bf(a.y); o[2] = f2bf(a.z); o[3] = f2bf(a.w);
        o[4] = f2bf(c.x); o[5] = f2bf(c.y); o[6] = f2bf(c.z); o[7] = f2bf(c.w);
        *reinterpret_cast<short8v*>(Kb + i) = o;
    } else if (b < PREP_CONV_BLOCKS + PREP_TRANS_BLOCKS) {
        __shared__ short Ts[DH][72];
        int b2 = b - PREP_CONV_BLOCKS;
        int bh = b2 >> 5;
        int t  = b2 & 31;
        const float* Vb = V + ((size_t)bh * S_LEN + t * KTI) * DH;
        int tid = threadIdx.x;
        #pragma unroll
        for (int i = 0; i < 4; ++i) {
            int lin = tid + i * 256;          // 0..1023 (float4 index)
            int row = lin >> 4;
            int c4  = (lin & 15) << 2;
            float4 v4 = *reinterpret_cast<const float4*>(Vb + row * DH + c4);
            Ts[c4 + 0][row] = f2bf(v4.x);
            Ts[c4 + 1][row] = f2bf(v4.y);
            Ts[c4 + 2][row] = f2bf(v4.z);
            Ts[c4 + 3][row] = f2bf(v4.w);
        }
        __syncthreads();
        #pragma unroll
        for (int i = 0; i < 2; ++i) {
            int lin = tid + i * 256;          // 0..511 (short8 index)
            int d   = lin >> 3;
            int k8  = (lin & 7) << 3;
            short8v o = *reinterpret_cast<const short8v*>(&Ts[d][k8]);
            *reinterpret_cast<short8v*>(Vt + ((size_t)bh * DH + d) * S_LEN + t * KTI + k8) = o;
        }
    } else {
        int tid = (b - PREP_CONV_BLOCKS - PREP_TRANS_BLOCKS) * 256 + threadIdx.x;
        int c  = tid & 15;
        int t  = (tid >> 4) & (NT - 1);
        int q4 = tid >> 9;
        uint32_t bits = 0;
        #pragma unroll
        for (int r = 0; r < 4; ++r)
            #pragma unroll
            for (int n = 0; n < 4; ++n) {
                int q = q4 * 4 + r;
                int k = t * KTI + n * 16 + c;
                if (mask[q * S_LEN + k]) bits |= 1u << (r * 4 + n);
            }
        pmL[tid] = bits;
    }
}

// ---------- main attention kernel (fused, 45KB LDS, 3 blocks/CU) ----------

__global__ __launch_bounds__(NTHR, 6)
void attn_kernel(const float* __restrict__ Q, const uint16_t* __restrict__ Kbf,
                 const uint16_t* __restrict__ VTb, const uint32_t* __restrict__ pmask,
                 float* __restrict__ outC, float* __restrict__ outA)
{
    __shared__ short Ks[2][KTI][72];     // double-buffered K tile     (18.4 KB)
    __shared__ short VT[DH][72];         // single-buffered V^T tile    (9.2 KB)
    __shared__ short Ps[8][16][72];      // per-wave P tile            (18.4 KB)

    // XCD-aware swizzle (T1): XCD c (= wg%8) serves bh in [8c, 8c+8); all 16
    // q-blocks of one bh consecutive -> per-XCD K/V working set ~512KB << 4MB L2.
    const int wg  = blockIdx.x;          // 0..1023
    const int k_  = wg >> 3;
    const int bh  = (wg & 7) * 8 + (k_ >> 4);
    const int q0  = (k_ & 15) * QR;

    const int tid = threadIdx.x;
    const int w   = tid >> 6;
    const int l   = tid & 63;
    const int l16 = l & 15;
    const int g   = l >> 4;
    const int srow = tid >> 3;           // staging row (0..63)
    const int scol = (tid & 7) << 3;     // staging col (0,8,...,56)

    const float*    Qb  = Q   + ((size_t)bh * S_LEN + q0) * DH;
    const uint16_t* Kbb = Kbf + (size_t)bh * S_LEN * DH;       // [s][d]
    const uint16_t* Vbb = VTb + (size_t)bh * DH * S_LEN;       // [d][s]
    float* Cb = outC + ((size_t)bh * S_LEN + q0) * DH;
    float* Ab = outA + (size_t)bh * S_LEN * S_LEN + (size_t)q0 * S_LEN;

    // ---- Q A-fragments loaded per-lane directly (no LDS; reused in both phases) ----
    short8v aq0, aq1;
    {
        const float* qp = Qb + (w * 16 + l16) * DH;
        float4 a0 = *reinterpret_cast<const float4*>(qp + g * 8);
        float4 a1 = *reinterpret_cast<const float4*>(qp + g * 8 + 4);
        float4 a2 = *reinterpret_cast<const float4*>(qp + 32 + g * 8);
        float4 a3 = *reinterpret_cast<const float4*>(qp + 32 + g * 8 + 4);
        aq0[0] = f2bf(a0.x); aq0[1] = f2bf(a0.y); aq0[2] = f2bf(a0.z); aq0[3] = f2bf(a0.w);
        aq0[4] = f2bf(a1.x); aq0[5] = f2bf(a1.y); aq0[6] = f2bf(a1.z); aq0[7] = f2bf(a1.w);
        aq1[0] = f2bf(a2.x); aq1[1] = f2bf(a2.y); aq1[2] = f2bf(a2.z); aq1[3] = f2bf(a2.w);
        aq1[4] = f2bf(a3.x); aq1[5] = f2bf(a3.y); aq1[6] = f2bf(a3.z); aq1[7] = f2bf(a3.w);
    }

    const uint32_t* pmb = pmask + (size_t)((q0 >> 2) + (w << 2) + g) * (NT * 16) + l16;

    // ================= phase 1: softmax denominators (fixed-bias, no max) =================
    float ls[4] = {0.f, 0.f, 0.f, 0.f};
    {
        short8v kk = *reinterpret_cast<const short8v*>(Kbb + (size_t)srow * DH + scol);
        *reinterpret_cast<short8v*>(&Ks[0][srow][scol]) = kk;
    }
    __syncthreads();

    for (int t = 0; t < NT; ++t) {
        const int  cur  = t & 1;
        const bool more = (t + 1 < NT);
        short8v nk;
        if (more)
            nk = *reinterpret_cast<const short8v*>(Kbb + (size_t)((t + 1) * KTI + srow) * DH + scol);

        uint32_t mb = pmb[t << 4];

        f32x4 acc[4];
        __builtin_amdgcn_s_setprio(1);
        #pragma unroll
        for (int n = 0; n < 4; ++n) {
            short8v b0 = *reinterpret_cast<const short8v*>(&Ks[cur][n * 16 + l16][g * 8]);
            short8v b1 = *reinterpret_cast<const short8v*>(&Ks[cur][n * 16 + l16][32 + g * 8]);
            f32x4 a = {0.f, 0.f, 0.f, 0.f};
            a = __builtin_amdgcn_mfma_f32_16x16x32_bf16(aq0, b0, a, 0, 0, 0);
            a = __builtin_amdgcn_mfma_f32_16x16x32_bf16(aq1, b1, a, 0, 0, 0);
            acc[n] = a;
        }
        __builtin_amdgcn_s_setprio(0);

        #pragma unroll
        for (int n = 0; n < 4; ++n)
            #pragma unroll
            for (int r = 0; r < 4; ++r) {
                float e = __builtin_amdgcn_exp2f(acc[n][r] * SCALE2 - EXPB2);
                ls[r] += ((mb >> (r * 4 + n)) & 1u) ? e : 0.f;
            }

        if (more)
            *reinterpret_cast<short8v*>(&Ks[cur ^ 1][srow][scol]) = nk;
        __syncthreads();
    }

    // reduce row sums across the 16-lane group, once
    float li[4];
    #pragma unroll
    for (int r = 0; r < 4; ++r) {
        float v = ls[r];
        v += __shfl_xor(v, 1);
        v += __shfl_xor(v, 2);
        v += __shfl_xor(v, 4);
        v += __shfl_xor(v, 8);
        li[r] = 1.0f / v;
    }

    f32x4 acco[4];
    #pragma unroll
    for (int n = 0; n < 4; ++n) acco[n] = (f32x4){0.f, 0.f, 0.f, 0.f};

    // ================= phase 2: attn write + PV =================
    {
        short8v kk = *reinterpret_cast<const short8v*>(Kbb + (size_t)srow * DH + scol);
        *reinterpret_cast<short8v*>(&Ks[0][srow][scol]) = kk;
        short8v vv = *reinterpret_cast<const short8v*>(Vbb + (size_t)srow * S_LEN + scol);
        *reinterpret_cast<short8v*>(&VT[srow][scol]) = vv;
    }
    __syncthreads();

    for (int t = 0; t < NT; ++t) {
        const int  cur  = t & 1;
        const bool more = (t + 1 < NT);
        short8v nk, nv;
        if (more) {
            nk = *reinterpret_cast<const short8v*>(Kbb + (size_t)((t + 1) * KTI + srow) * DH + scol);
            nv = *reinterpret_cast<const short8v*>(Vbb + (size_t)srow * S_LEN + (t + 1) * KTI + scol);
        }
        uint32_t mb = pmb[t << 4];

        f32x4 acc[4];
        __builtin_amdgcn_s_setprio(1);
        #pragma unroll
        for (int n = 0; n < 4; ++n) {
            short8v b0 = *reinterpret_cast<const short8v*>(&Ks[cur][n * 16 + l16][g * 8]);
            short8v b1 = *reinterpret_cast<const short8v*>(&Ks[cur][n * 16 + l16][32 + g * 8]);
            f32x4 a = {0.f, 0.f, 0.f, 0.f};
            a = __builtin_amdgcn_mfma_f32_16x16x32_bf16(aq0, b0, a, 0, 0, 0);
            a = __builtin_amdgcn_mfma_f32_16x16x32_bf16(aq1, b1, a, 0, 0, 0);
            acc[n] = a;
        }
        __builtin_amdgcn_s_setprio(0);

        // normalized probabilities -> Ps (bf16, A-frag layout)
        #pragma unroll
        for (int n = 0; n < 4; ++n)
            #pragma unroll
            for (int r = 0; r < 4; ++r) {
                float e = __builtin_amdgcn_exp2f(acc[n][r] * SCALE2 - EXPB2) * li[r];
                float p = ((mb >> (r * 4 + n)) & 1u) ? e : 0.0f;
                Ps[w][4 * g + r][n * 16 + l16] = f2bf(p);
            }

        // order the Ps short-writes before the vector readback (TBAA-proof)
        asm volatile("" ::: "memory");

        // attn store: full 256B row-chunks as f32x4, nontemporal (no L2 pollution)
        {
            float* Aw = Ab + (size_t)(w * 16) * S_LEN + t * KTI;
            #pragma unroll
            for (int j = 0; j < 4; ++j) {
                int r4 = 4 * j + (l >> 4);
                short4v pv4 = *reinterpret_cast<const short4v*>(&Ps[w][r4][(l & 15) * 4]);
                f32x4 o;
                o[0] = __builtin_bit_cast(float, ((uint32_t)(uint16_t)pv4[0]) << 16);
                o[1] = __builtin_bit_cast(float, ((uint32_t)(uint16_t)pv4[1]) << 16);
                o[2] = __builtin_bit_cast(float, ((uint32_t)(uint16_t)pv4[2]) << 16);
                o[3] = __builtin_bit_cast(float, ((uint32_t)(uint16_t)pv4[3]) << 16);
                __builtin_nontemporal_store(o,
                    reinterpret_cast<f32x4*>(Aw + (size_t)r4 * S_LEN + (l & 15) * 4));
            }
        }

        // PV: O += P(16xKTI) * V(KTIxDH)
        short8v ap0 = *reinterpret_cast<const short8v*>(&Ps[w][l16][g * 8]);
        short8v ap1 = *reinterpret_cast<const short8v*>(&Ps[w][l16][32 + g * 8]);
        __builtin_amdgcn_s_setprio(1);
        #pragma unroll
        for (int n = 0; n < 4; ++n) {
            short8v b0 = *reinterpret_cast<const short8v*>(&VT[n * 16 + l16][g * 8]);
            short8v b1 = *reinterpret_cast<const short8v*>(&VT[n * 16 + l16][32 + g * 8]);
            acco[n] = __builtin_amdgcn_mfma_f32_16x16x32_bf16(ap0, b0, acco[n], 0, 0, 0);
            acco[n] = __builtin_amdgcn_mfma_f32_16x16x32_bf16(ap1, b1, acco[n], 0, 0, 0);
        }
        __builtin_amdgcn_s_setprio(0);

        // K is double-buffered: safe to write cur^1 before the barrier
        if (more)
            *reinterpret_cast<short8v*>(&Ks[cur ^ 1][srow][scol]) = nk;
        __syncthreads();                  // all PV reads of VT complete
        if (more)
            *reinterpret_cast<short8v*>(&VT[srow][scol]) = nv;
        __syncthreads();                  // staged K/V visible for next tile
    }

    // ---- write context ----
    #pragma unroll
    for (int n = 0; n < 4; ++n)
        #pragma unroll
        for (int r = 0; r < 4; ++r)
            Cb[(w * 16 + 4 * g + r) * DH + n * 16 + l16] = acco[n][r];
}

extern "C" void kernel_launch(void* const* d_in, const int* in_sizes, int n_in,
                              void* d_out, int out_size, void* d_ws, size_t ws_size,
                              hipStream_t stream)
{
    const float* Q    = (const float*)d_in[0];
    const float* K    = (const float*)d_in[1];
    const float* V    = (const float*)d_in[2];
    const int*   mask = (const int*)d_in[3];

    float* outC = (float*)d_out;
    float* outA = (float*)d_out + (size_t)NBH * S_LEN * DH;   // context first, then attn

    char* ws = (char*)d_ws;
    uint32_t* pmL = (uint32_t*)ws;                             // 1 MB packed mask
    uint16_t* Kbf = (uint16_t*)(ws + (1 << 20));               // 16 MB bf16 K
    uint16_t* VTb = (uint16_t*)(ws + (17 << 20));              // 16 MB bf16 V^T

    prep_kernel<<<dim3(PREP_CONV_BLOCKS + PREP_TRANS_BLOCKS + PREP_MASK_BLOCKS),
                  256, 0, stream>>>(K, V, mask, Kbf, VTb, pmL);
    attn_kernel<<<dim3(NBH * (S_LEN / QR)), NTHR, 0, stream>>>(Q, Kbf, VTb, pmL, outC, outA);
}